// Round 12
// baseline (102.022 us; speedup 1.0000x reference)
//
#include <hip/hip_runtime.h>

typedef short short8 __attribute__((ext_vector_type(8)));
typedef float f32x4 __attribute__((ext_vector_type(4)));
typedef unsigned long long u64;

#define NE 1024
#define D 64
#define HW 4096
#define NTOK 65536
#define MARGIN 3.0e-3f
#define FLT_MAX_F 3.402823466e+38f

// ws (<=262KB proven): bn f32[1024]@0 ; ebf u16[65536]@4096 ; win u16[65536]@135168
#define WS_BN  0
#define WS_EBF 4096
#define WS_WIN 135168
// d_out overlay (16MB, fully overwritten by k3_gather):
//   mask u64[65536*16] @0 (8MB) ; gmin u32[65536] @8388608 (256KB)

__device__ __forceinline__ unsigned short f2bf(float f) {   // RNE f32->bf16
    unsigned u = __float_as_uint(f);
    return (unsigned short)((u + 0x7fffu + ((u >> 16) & 1u)) >> 16);
}

// order-preserving f32 <-> u32 bijection (valid for ALL signs; R10 bug fix:
// t = ||e||^2 - 2 x.e is typically NEGATIVE, raw-bits u32 order breaks there)
__device__ __forceinline__ unsigned fenc(float f) {
    unsigned u = __float_as_uint(f);
    return (u & 0x80000000u) ? ~u : (u | 0x80000000u);
}
__device__ __forceinline__ float fdec(unsigned u) {
    unsigned v = (u & 0x80000000u) ? (u & 0x7FFFFFFFu) : ~u;
    return __uint_as_float(v);
}

// numpy pairwise sum of squares, n=64 (frozen — exact since R2)
__device__ __forceinline__ float np_sum64_sq(const float* v) {
    float s[8];
#pragma unroll
    for (int j = 0; j < 8; ++j) s[j] = __fmul_rn(v[j], v[j]);
#pragma unroll
    for (int i = 8; i < 64; i += 8) {
#pragma unroll
        for (int j = 0; j < 8; ++j)
            s[j] = __fadd_rn(s[j], __fmul_rn(v[i + j], v[i + j]));
    }
    return __fadd_rn(__fadd_rn(__fadd_rn(s[0], s[1]), __fadd_rn(s[2], s[3])),
                     __fadd_rn(__fadd_rn(s[4], s[5]), __fadd_rn(s[6], s[7])));
}

__global__ __launch_bounds__(256) void kP_prep(
        const float* __restrict__ cb, float* __restrict__ bn,
        unsigned short* __restrict__ ebf, u64* __restrict__ mask,
        unsigned* __restrict__ gmin) {
    const int gid = blockIdx.x * 256 + threadIdx.x;   // 65536 threads
    // zero the 8 MB mask (128 B/thread, coalesced)
    int4 z = {0, 0, 0, 0};
    int4* mz = (int4*)mask;
#pragma unroll
    for (int i = 0; i < 8; ++i) mz[(size_t)gid * 8 + i] = z;
    gmin[gid] = 0xFFFFFFFFu;                  // fenc(+inf)-ish: max encoded value
    ebf[gid] = f2bf(cb[gid]);
    if (gid < NE) {
        float row[D];
        const float4* r4 = reinterpret_cast<const float4*>(cb + (size_t)gid * D);
#pragma unroll
        for (int i = 0; i < 16; ++i) {
            float4 v = r4[i];
            row[4*i+0] = v.x; row[4*i+1] = v.y; row[4*i+2] = v.z; row[4*i+3] = v.w;
        }
        bn[gid] = np_sum64_sq(row);
    }
}

// ---- shared k1 body pieces (staging + frag rebuild, proven R6-R10) ----
#define K1_HEAD                                                               \
    __shared__ unsigned short ebq[128 * 64];                                  \
    __shared__ float sbn[128];                                                \
    const int sw  = (blockIdx.x & 7) * 512 + (blockIdx.x >> 3);               \
    const int tg  = sw >> 3;                                                  \
    const int c   = sw & 7;                                                   \
    const int tid  = threadIdx.x;                                             \
    const int lane = tid & 63, w = tid >> 6;                                  \
    const int lcol = lane & 15, lhi = lane >> 4, lrow = lhi * 4;              \
    const int tokw = tg * 128 + w * 32;                                       \
    if (tid < 128) sbn[tid] = bn_g[c * 128 + tid];                            \
    const char* src = (const char*)(ebf + (size_t)c * 128 * 64);              \
    _Pragma("unroll")                                                         \
    for (int i = 0; i < 4; ++i) {                                             \
        int L = (tid + i * 256) * 16;                                         \
        int row = L >> 7, wi = L & 127;                                       \
        int4 v = *(const int4*)(src + L);                                     \
        *(int4*)((char*)ebq + row * 128 + (wi ^ ((row & 7) << 4))) = v;       \
    }                                                                         \
    const int b = tokw >> 12, hwb = tokw & 4095;                              \
    const float* xbase = in + (size_t)b * (D * HW);                           \
    const int hw0 = hwb + lcol, hw1 = hw0 + 16;                               \
    const int kb = lhi * 8;                                                   \
    short8 B00, B01, B10, B11;                                                \
    {                                                                         \
        const float* p;                                                       \
        p = xbase + (size_t)kb * HW + hw0;                                    \
        _Pragma("unroll")                                                     \
        for (int j = 0; j < 8; ++j) B00[j] = (short)f2bf(p[(size_t)j * HW]);  \
        p = xbase + (size_t)(kb + 32) * HW + hw0;                             \
        _Pragma("unroll")                                                     \
        for (int j = 0; j < 8; ++j) B01[j] = (short)f2bf(p[(size_t)j * HW]);  \
        p = xbase + (size_t)kb * HW + hw1;                                    \
        _Pragma("unroll")                                                     \
        for (int j = 0; j < 8; ++j) B10[j] = (short)f2bf(p[(size_t)j * HW]);  \
        p = xbase + (size_t)(kb + 32) * HW + hw1;                             \
        _Pragma("unroll")                                                     \
        for (int j = 0; j < 8; ++j) B11[j] = (short)f2bf(p[(size_t)j * HW]);  \
    }                                                                         \
    __syncthreads();                                                          \
    const int swz   = (lcol & 7) << 4;                                        \
    const int aoff0 = lcol * 128 + ((lhi * 16) ^ swz);                        \
    const int aoff1 = lcol * 128 + ((64 + lhi * 16) ^ swz);

#define K1_MFMA(CT)                                                           \
    const char* lp = (const char*)ebq + (CT) * 2048;                          \
    short8 A0 = *(const short8*)(lp + aoff0);                                 \
    short8 A1 = *(const short8*)(lp + aoff1);                                 \
    f32x4 bnv = *(const f32x4*)(sbn + (CT) * 16 + lrow);                      \
    f32x4 acc = {0.f, 0.f, 0.f, 0.f};                                         \
    acc = __builtin_amdgcn_mfma_f32_16x16x32_bf16(A0, B00, acc, 0, 0, 0);     \
    acc = __builtin_amdgcn_mfma_f32_16x16x32_bf16(A1, B01, acc, 0, 0, 0);     \
    f32x4 ac2 = {0.f, 0.f, 0.f, 0.f};                                         \
    ac2 = __builtin_amdgcn_mfma_f32_16x16x32_bf16(A0, B10, ac2, 0, 0, 0);     \
    ac2 = __builtin_amdgcn_mfma_f32_16x16x32_bf16(A1, B11, ac2, 0, 0, 0);

// pass A: per-token min over this chunk -> atomicMin(gmin) (fire-and-forget)
__global__ __launch_bounds__(256, 4) void k1a_min(
        const float* __restrict__ in, const unsigned short* __restrict__ ebf,
        const float* __restrict__ bn_g, unsigned* __restrict__ gmin) {
    K1_HEAD
    float v10 = FLT_MAX_F, v11 = FLT_MAX_F;
#pragma unroll
    for (int ct = 0; ct < 8; ++ct) {
        K1_MFMA(ct)
#pragma unroll
        for (int r = 0; r < 4; ++r) {
            v10 = fminf(v10, __fmaf_rn(-2.0f, acc[r], bnv[r]));
            v11 = fminf(v11, __fmaf_rn(-2.0f, ac2[r], bnv[r]));
        }
    }
    v10 = fminf(v10, __shfl_xor(v10, 16)); v10 = fminf(v10, __shfl_xor(v10, 32));
    v11 = fminf(v11, __shfl_xor(v11, 16)); v11 = fminf(v11, __shfl_xor(v11, 32));
    // sign-aware order-preserving encode (R10 bugfix)
    if (lhi == 0) atomicMin(&gmin[tokw + lcol],      fenc(v10));
    if (lhi == 1) atomicMin(&gmin[tokw + 16 + lcol], fenc(v11));
}

// pass B: recompute t (bit-identical) and mark t <= gmin+MARGIN into bitmask
__global__ __launch_bounds__(256, 4) void k1b_mark(
        const float* __restrict__ in, const unsigned short* __restrict__ ebf,
        const float* __restrict__ bn_g, const unsigned* __restrict__ gmin,
        u64* __restrict__ mask) {
    K1_HEAD
    const float thr0 = fdec(gmin[tokw + lcol]) + MARGIN;
    const float thr1 = fdec(gmin[tokw + 16 + lcol]) + MARGIN;
    u64* mrow0 = mask + (size_t)(tokw + lcol) * 16;
    u64* mrow1 = mask + (size_t)(tokw + 16 + lcol) * 16;
#pragma unroll
    for (int ct = 0; ct < 8; ++ct) {
        K1_MFMA(ct)
        const int kg = c * 128 + ct * 16 + lrow;
#pragma unroll
        for (int r = 0; r < 4; ++r) {
            float t0 = __fmaf_rn(-2.0f, acc[r], bnv[r]);
            if (t0 <= thr0) atomicOr(&mrow0[(kg + r) >> 6], 1ull << ((kg + r) & 63));
            float t1 = __fmaf_rn(-2.0f, ac2[r], bnv[r]);
            if (t1 <= thr1) atomicOr(&mrow1[(kg + r) >> 6], 1ull << ((kg + r) & 63));
        }
    }
}

// thread per token: frozen-exact rerank of masked candidates, pairwise ILP
__global__ __launch_bounds__(256, 4) void k2_rerank(
        const float* __restrict__ in, const float* __restrict__ cb,
        const float* __restrict__ bn, const u64* __restrict__ mask,
        unsigned short* __restrict__ win) {
    const int tok = blockIdx.x * 256 + threadIdx.x;
    const int b = tok >> 12, hw = tok & 4095;
    const float* x = in + (size_t)b * (D * HW) + hw;
    float xv[D];
#pragma unroll
    for (int d = 0; d < D; ++d) xv[d] = x[(size_t)d * HW];   // coalesced across wave
    const float a = np_sum64_sq(xv);                          // frozen

    u64 best = ~0ull;
    int kp = -1;
    for (int wd = 0; wd < 16; ++wd) {
        u64 m = mask[(size_t)tok * 16 + wd];
        while (m) {
            const int k = wd * 64 + (int)__builtin_ctzll(m);
            m &= m - 1;
            if (kp < 0) { kp = k; continue; }
            // pair: two independent frozen chains (each sequential asc d)
            const float* e0 = cb + (size_t)kp * D;
            const float* e1 = cb + (size_t)k * D;
            float d0 = 0.f, d1 = 0.f;
#pragma unroll
            for (int d = 0; d < 64; ++d) {
                d0 = __fmaf_rn(xv[d], e0[d], d0);
                d1 = __fmaf_rn(xv[d], e1[d], d1);
            }
            float q0 = __fsub_rn(__fadd_rn(a, bn[kp]), __fmul_rn(2.0f, d0));  // frozen
            float q1 = __fsub_rn(__fadd_rn(a, bn[k]),  __fmul_rn(2.0f, d1));  // frozen
            u64 key0 = (((u64)__float_as_uint(q0)) << 32) | (unsigned)kp;
            u64 key1 = (((u64)__float_as_uint(q1)) << 32) | (unsigned)k;
            u64 kmin = key0 < key1 ? key0 : key1;
            best = best < kmin ? best : kmin;   // lexicographic (q,k) = np argmin (q>0)
            kp = -1;
        }
    }
    if (kp >= 0) {                              // leftover single
        const float* e0 = cb + (size_t)kp * D;
        float d0 = 0.f;
#pragma unroll
        for (int d = 0; d < 64; ++d) d0 = __fmaf_rn(xv[d], e0[d], d0);
        float q0 = __fsub_rn(__fadd_rn(a, bn[kp]), __fmul_rn(2.0f, d0));
        u64 key0 = (((u64)__float_as_uint(q0)) << 32) | (unsigned)kp;
        best = best < key0 ? best : key0;
    }
    win[tok] = (unsigned short)(best & 0x3FFull);
}

__global__ __launch_bounds__(256) void k3_gather(
        const float* __restrict__ cb, const unsigned short* __restrict__ win,
        float* __restrict__ out) {
    const int gid = blockIdx.x * 256 + threadIdx.x;   // 262144 threads
    const int tok = gid >> 2, qd = (gid & 3) << 4;
    const int b = tok >> 12, hw = tok & 4095;
    const unsigned k = win[tok];
    const float4* er = reinterpret_cast<const float4*>(cb + (size_t)k * D + qd);
    float* ot = out + (size_t)b * (D * HW) + hw;
#pragma unroll
    for (int i = 0; i < 4; ++i) {
        float4 e = er[i];
        ot[(size_t)(qd + 4*i + 0) * HW] = e.x;
        ot[(size_t)(qd + 4*i + 1) * HW] = e.y;
        ot[(size_t)(qd + 4*i + 2) * HW] = e.z;
        ot[(size_t)(qd + 4*i + 3) * HW] = e.w;
    }
}

extern "C" void kernel_launch(void* const* d_in, const int* in_sizes, int n_in,
                              void* d_out, int out_size, void* d_ws, size_t ws_size,
                              hipStream_t stream) {
    const float* in  = (const float*)d_in[0];
    const float* cb  = (const float*)d_in[1];
    float*       out = (float*)d_out;
    char*        ws  = (char*)d_ws;

    float*          bn   = (float*)(ws + WS_BN);
    unsigned short* ebf  = (unsigned short*)(ws + WS_EBF);
    unsigned short* win  = (unsigned short*)(ws + WS_WIN);
    u64*            mask = (u64*)d_out;
    unsigned*       gmin = (unsigned*)((char*)d_out + 8388608);

    hipLaunchKernelGGL(kP_prep,   dim3(256),  dim3(256), 0, stream, cb, bn, ebf, mask, gmin);
    hipLaunchKernelGGL(k1a_min,   dim3(4096), dim3(256), 0, stream, in, ebf, bn, gmin);
    hipLaunchKernelGGL(k1b_mark,  dim3(4096), dim3(256), 0, stream, in, ebf, bn, gmin, mask);
    hipLaunchKernelGGL(k2_rerank, dim3(256),  dim3(256), 0, stream, in, cb, bn, mask, win);
    hipLaunchKernelGGL(k3_gather, dim3(1024), dim3(256), 0, stream, cb, win, out);
}

// Round 13
// 87.030 us; speedup vs baseline: 1.1723x; 1.1723x over previous
//
#include <hip/hip_runtime.h>

typedef short short8 __attribute__((ext_vector_type(8)));
typedef float f32x4 __attribute__((ext_vector_type(4)));
typedef unsigned long long u64;

#define NE 1024
#define D 64
#define HW 4096
#define NTOK 65536
#define MARGIN 3.0e-3f
#define FLT_MAX_F 3.402823466e+38f

// ws (<=262KB proven): bn f32[1024]@0 ; ebf u16[65536]@4096 ; win u16[65536]@135168
#define WS_BN  0
#define WS_EBF 4096
#define WS_WIN 135168
// d_out overlay (16MB, fully overwritten by k3_gather):
//   mask u64[65536*16] @0 (8MB) ; gmin u32[65536] @8388608 (256KB)

__device__ __forceinline__ unsigned short f2bf(float f) {   // RNE f32->bf16
    unsigned u = __float_as_uint(f);
    return (unsigned short)((u + 0x7fffu + ((u >> 16) & 1u)) >> 16);
}

// order-preserving f32 <-> u32 bijection (R10 bugfix, proven R12)
__device__ __forceinline__ unsigned fenc(float f) {
    unsigned u = __float_as_uint(f);
    return (u & 0x80000000u) ? ~u : (u | 0x80000000u);
}
__device__ __forceinline__ float fdec(unsigned u) {
    unsigned v = (u & 0x80000000u) ? (u & 0x7FFFFFFFu) : ~u;
    return __uint_as_float(v);
}

// numpy pairwise sum of squares, n=64 (frozen — exact since R2)
__device__ __forceinline__ float np_sum64_sq(const float* v) {
    float s[8];
#pragma unroll
    for (int j = 0; j < 8; ++j) s[j] = __fmul_rn(v[j], v[j]);
#pragma unroll
    for (int i = 8; i < 64; i += 8) {
#pragma unroll
        for (int j = 0; j < 8; ++j)
            s[j] = __fadd_rn(s[j], __fmul_rn(v[i + j], v[i + j]));
    }
    return __fadd_rn(__fadd_rn(__fadd_rn(s[0], s[1]), __fadd_rn(s[2], s[3])),
                     __fadd_rn(__fadd_rn(s[4], s[5]), __fadd_rn(s[6], s[7])));
}

__global__ __launch_bounds__(256) void kP_prep(
        const float* __restrict__ cb, float* __restrict__ bn,
        unsigned short* __restrict__ ebf, u64* __restrict__ mask,
        unsigned* __restrict__ gmin) {
    const int gid = blockIdx.x * 256 + threadIdx.x;   // 65536 threads
    int4 z = {0, 0, 0, 0};
    int4* mz = (int4*)mask;
#pragma unroll
    for (int i = 0; i < 8; ++i) mz[(size_t)gid * 8 + i] = z;
    gmin[gid] = 0xFFFFFFFFu;                  // max encoded value
    ebf[gid] = f2bf(cb[gid]);
    if (gid < NE) {
        float row[D];
        const float4* r4 = reinterpret_cast<const float4*>(cb + (size_t)gid * D);
#pragma unroll
        for (int i = 0; i < 16; ++i) {
            float4 v = r4[i];
            row[4*i+0] = v.x; row[4*i+1] = v.y; row[4*i+2] = v.z; row[4*i+3] = v.w;
        }
        bn[gid] = np_sum64_sq(row);
    }
}

// ---- shared k1 body pieces (staging + frag rebuild, proven R6-R12) ----
#define K1_HEAD                                                               \
    __shared__ unsigned short ebq[128 * 64];                                  \
    __shared__ float sbn[128];                                                \
    const int sw  = (blockIdx.x & 7) * 512 + (blockIdx.x >> 3);               \
    const int tg  = sw >> 3;                                                  \
    const int c   = sw & 7;                                                   \
    const int tid  = threadIdx.x;                                             \
    const int lane = tid & 63, w = tid >> 6;                                  \
    const int lcol = lane & 15, lhi = lane >> 4, lrow = lhi * 4;              \
    const int tokw = tg * 128 + w * 32;                                       \
    if (tid < 128) sbn[tid] = bn_g[c * 128 + tid];                            \
    const char* src = (const char*)(ebf + (size_t)c * 128 * 64);              \
    _Pragma("unroll")                                                         \
    for (int i = 0; i < 4; ++i) {                                             \
        int L = (tid + i * 256) * 16;                                         \
        int row = L >> 7, wi = L & 127;                                       \
        int4 v = *(const int4*)(src + L);                                     \
        *(int4*)((char*)ebq + row * 128 + (wi ^ ((row & 7) << 4))) = v;       \
    }                                                                         \
    const int b = tokw >> 12, hwb = tokw & 4095;                              \
    const float* xbase = in + (size_t)b * (D * HW);                           \
    const int hw0 = hwb + lcol, hw1 = hw0 + 16;                               \
    const int kb = lhi * 8;                                                   \
    short8 B00, B01, B10, B11;                                                \
    {                                                                         \
        const float* p;                                                       \
        p = xbase + (size_t)kb * HW + hw0;                                    \
        _Pragma("unroll")                                                     \
        for (int j = 0; j < 8; ++j) B00[j] = (short)f2bf(p[(size_t)j * HW]);  \
        p = xbase + (size_t)(kb + 32) * HW + hw0;                             \
        _Pragma("unroll")                                                     \
        for (int j = 0; j < 8; ++j) B01[j] = (short)f2bf(p[(size_t)j * HW]);  \
        p = xbase + (size_t)kb * HW + hw1;                                    \
        _Pragma("unroll")                                                     \
        for (int j = 0; j < 8; ++j) B10[j] = (short)f2bf(p[(size_t)j * HW]);  \
        p = xbase + (size_t)(kb + 32) * HW + hw1;                             \
        _Pragma("unroll")                                                     \
        for (int j = 0; j < 8; ++j) B11[j] = (short)f2bf(p[(size_t)j * HW]);  \
    }                                                                         \
    __syncthreads();                                                          \
    const int swz   = (lcol & 7) << 4;                                        \
    const int aoff0 = lcol * 128 + ((lhi * 16) ^ swz);                        \
    const int aoff1 = lcol * 128 + ((64 + lhi * 16) ^ swz);

#define K1_MFMA(CT)                                                           \
    const char* lp = (const char*)ebq + (CT) * 2048;                          \
    short8 A0 = *(const short8*)(lp + aoff0);                                 \
    short8 A1 = *(const short8*)(lp + aoff1);                                 \
    f32x4 bnv = *(const f32x4*)(sbn + (CT) * 16 + lrow);                      \
    f32x4 acc = {0.f, 0.f, 0.f, 0.f};                                         \
    acc = __builtin_amdgcn_mfma_f32_16x16x32_bf16(A0, B00, acc, 0, 0, 0);     \
    acc = __builtin_amdgcn_mfma_f32_16x16x32_bf16(A1, B01, acc, 0, 0, 0);     \
    f32x4 ac2 = {0.f, 0.f, 0.f, 0.f};                                         \
    ac2 = __builtin_amdgcn_mfma_f32_16x16x32_bf16(A0, B10, ac2, 0, 0, 0);     \
    ac2 = __builtin_amdgcn_mfma_f32_16x16x32_bf16(A1, B11, ac2, 0, 0, 0);

// pass A: per-token min over this chunk -> atomicMin(gmin) (fire-and-forget)
__global__ __launch_bounds__(256, 4) void k1a_min(
        const float* __restrict__ in, const unsigned short* __restrict__ ebf,
        const float* __restrict__ bn_g, unsigned* __restrict__ gmin) {
    K1_HEAD
    float v10 = FLT_MAX_F, v11 = FLT_MAX_F;
#pragma unroll
    for (int ct = 0; ct < 8; ++ct) {
        K1_MFMA(ct)
#pragma unroll
        for (int r = 0; r < 4; ++r) {
            v10 = fminf(v10, __fmaf_rn(-2.0f, acc[r], bnv[r]));
            v11 = fminf(v11, __fmaf_rn(-2.0f, ac2[r], bnv[r]));
        }
    }
    v10 = fminf(v10, __shfl_xor(v10, 16)); v10 = fminf(v10, __shfl_xor(v10, 32));
    v11 = fminf(v11, __shfl_xor(v11, 16)); v11 = fminf(v11, __shfl_xor(v11, 32));
    if (lhi == 0) atomicMin(&gmin[tokw + lcol],      fenc(v10));
    if (lhi == 1) atomicMin(&gmin[tokw + 16 + lcol], fenc(v11));
}

// pass B: recompute t (bit-identical) and mark t <= gmin+MARGIN into bitmask
__global__ __launch_bounds__(256, 4) void k1b_mark(
        const float* __restrict__ in, const unsigned short* __restrict__ ebf,
        const float* __restrict__ bn_g, const unsigned* __restrict__ gmin,
        u64* __restrict__ mask) {
    K1_HEAD
    const float thr0 = fdec(gmin[tokw + lcol]) + MARGIN;
    const float thr1 = fdec(gmin[tokw + 16 + lcol]) + MARGIN;
    u64* mrow0 = mask + (size_t)(tokw + lcol) * 16;
    u64* mrow1 = mask + (size_t)(tokw + 16 + lcol) * 16;
#pragma unroll
    for (int ct = 0; ct < 8; ++ct) {
        K1_MFMA(ct)
        const int kg = c * 128 + ct * 16 + lrow;
#pragma unroll
        for (int r = 0; r < 4; ++r) {
            float t0 = __fmaf_rn(-2.0f, acc[r], bnv[r]);
            if (t0 <= thr0) atomicOr(&mrow0[(kg + r) >> 6], 1ull << ((kg + r) & 63));
            float t1 = __fmaf_rn(-2.0f, ac2[r], bnv[r]);
            if (t1 <= thr1) atomicOr(&mrow1[(kg + r) >> 6], 1ull << ((kg + r) & 63));
        }
    }
}

// 8 threads per token: sub-th candidate (ordinal mod 8); frozen-exact rerank.
// u64 (q,k) key min is order-independent -> split+reduce is semantics-preserving.
__global__ __launch_bounds__(256, 4) void k2_rerank(
        const float* __restrict__ in, const float* __restrict__ cb,
        const float* __restrict__ bn, const u64* __restrict__ mask,
        unsigned short* __restrict__ win) {
    const int gid = blockIdx.x * 256 + threadIdx.x;   // 524288 threads
    const int tok = gid >> 3, sub = gid & 7;
    const int b = tok >> 12, hw = tok & 4095;
    const float* x = in + (size_t)b * (D * HW) + hw;
    float xv[D];
#pragma unroll
    for (int d = 0; d < D; ++d) xv[d] = x[(size_t)d * HW];   // 8 lanes share lines
    const float a = np_sum64_sq(xv);                          // frozen

    u64 best = ~0ull;
    int kp = -1;
    int pos = 0;
    for (int wd = 0; wd < 16; ++wd) {
        u64 m = mask[(size_t)tok * 16 + wd];
        while (m) {
            const int k = wd * 64 + (int)__builtin_ctzll(m);
            m &= m - 1;
            if (((pos++) & 7) != sub) continue;
            if (kp < 0) { kp = k; continue; }
            // pair: two independent frozen chains (each sequential asc d)
            const float* e0 = cb + (size_t)kp * D;
            const float* e1 = cb + (size_t)k * D;
            float d0 = 0.f, d1 = 0.f;
#pragma unroll
            for (int d = 0; d < 64; ++d) {
                d0 = __fmaf_rn(xv[d], e0[d], d0);
                d1 = __fmaf_rn(xv[d], e1[d], d1);
            }
            float q0 = __fsub_rn(__fadd_rn(a, bn[kp]), __fmul_rn(2.0f, d0));  // frozen
            float q1 = __fsub_rn(__fadd_rn(a, bn[k]),  __fmul_rn(2.0f, d1));  // frozen
            u64 key0 = (((u64)__float_as_uint(q0)) << 32) | (unsigned)kp;
            u64 key1 = (((u64)__float_as_uint(q1)) << 32) | (unsigned)k;
            u64 kmin = key0 < key1 ? key0 : key1;
            best = best < kmin ? best : kmin;
            kp = -1;
        }
    }
    if (kp >= 0) {                              // leftover single
        const float* e0 = cb + (size_t)kp * D;
        float d0 = 0.f;
#pragma unroll
        for (int d = 0; d < 64; ++d) d0 = __fmaf_rn(xv[d], e0[d], d0);
        float q0 = __fsub_rn(__fadd_rn(a, bn[kp]), __fmul_rn(2.0f, d0));
        u64 key0 = (((u64)__float_as_uint(q0)) << 32) | (unsigned)kp;
        best = best < key0 ? best : key0;
    }
    // reduce across the token's 8 sub-lanes (lanes 8t..8t+7 within the wave)
#pragma unroll
    for (int o = 1; o < 8; o <<= 1) {
        u64 v = __shfl_xor(best, o);
        best = best < v ? best : v;
    }
    if (sub == 0) win[tok] = (unsigned short)(best & 0x3FFull);
}

__global__ __launch_bounds__(256) void k3_gather(
        const float* __restrict__ cb, const unsigned short* __restrict__ win,
        float* __restrict__ out) {
    const int gid = blockIdx.x * 256 + threadIdx.x;   // 262144 threads
    const int tok = gid >> 2, qd = (gid & 3) << 4;
    const int b = tok >> 12, hw = tok & 4095;
    const unsigned k = win[tok];
    const float4* er = reinterpret_cast<const float4*>(cb + (size_t)k * D + qd);
    float* ot = out + (size_t)b * (D * HW) + hw;
#pragma unroll
    for (int i = 0; i < 4; ++i) {
        float4 e = er[i];
        ot[(size_t)(qd + 4*i + 0) * HW] = e.x;
        ot[(size_t)(qd + 4*i + 1) * HW] = e.y;
        ot[(size_t)(qd + 4*i + 2) * HW] = e.z;
        ot[(size_t)(qd + 4*i + 3) * HW] = e.w;
    }
}

extern "C" void kernel_launch(void* const* d_in, const int* in_sizes, int n_in,
                              void* d_out, int out_size, void* d_ws, size_t ws_size,
                              hipStream_t stream) {
    const float* in  = (const float*)d_in[0];
    const float* cb  = (const float*)d_in[1];
    float*       out = (float*)d_out;
    char*        ws  = (char*)d_ws;

    float*          bn   = (float*)(ws + WS_BN);
    unsigned short* ebf  = (unsigned short*)(ws + WS_EBF);
    unsigned short* win  = (unsigned short*)(ws + WS_WIN);
    u64*            mask = (u64*)d_out;
    unsigned*       gmin = (unsigned*)((char*)d_out + 8388608);

    hipLaunchKernelGGL(kP_prep,   dim3(256),  dim3(256), 0, stream, cb, bn, ebf, mask, gmin);
    hipLaunchKernelGGL(k1a_min,   dim3(4096), dim3(256), 0, stream, in, ebf, bn, gmin);
    hipLaunchKernelGGL(k1b_mark,  dim3(4096), dim3(256), 0, stream, in, ebf, bn, gmin, mask);
    hipLaunchKernelGGL(k2_rerank, dim3(2048), dim3(256), 0, stream, in, cb, bn, mask, win);
    hipLaunchKernelGGL(k3_gather, dim3(1024), dim3(256), 0, stream, cb, win, out);
}